// Round 1
// baseline (729.646 us; speedup 1.0000x reference)
//
#include <hip/hip_runtime.h>

#define B_SZ 16
#define L_SZ 2048
#define DIN 64
#define H_SZ 256
#define NH 32
#define NL 4
#define TC 128
#define NTC 16

typedef __attribute__((ext_vector_type(8))) __bf16 bf16x8;
typedef __attribute__((ext_vector_type(4))) float f32x4;

__device__ __forceinline__ unsigned short f2b(float f) {
  unsigned int u = __builtin_bit_cast(unsigned int, f);
  unsigned int r = u + 0x7fffu + ((u >> 16) & 1u);  // RNE (no NaN inputs here)
  return (unsigned short)(r >> 16);
}
__device__ __forceinline__ float b2f(unsigned short u) {
  unsigned int v = ((unsigned int)u) << 16;
  return __builtin_bit_cast(float, v);
}

// ---------------- encoder: h[b][hh][l] = x[b][l][:] @ enc_w[:,hh] + enc_b ----------------
__global__ void k_encoder(const float* __restrict__ x, const float* __restrict__ w,
                          const float* __restrict__ bias, float* __restrict__ hbuf) {
  __shared__ float wlds[DIN * H_SZ];  // 64 KB
  int tid = threadIdx.x;
  for (int i = tid; i < DIN * H_SZ; i += 256) wlds[i] = w[i];
  int blk = blockIdx.x;            // 512 blocks: b(16) x q(4) x ltile(8)
  int b = blk >> 5;
  int q = (blk >> 3) & 3;
  int l = ((blk & 7) << 8) + tid;
  float xr[DIN];
  const float4* xp = (const float4*)(x + (size_t)(b * L_SZ + l) * DIN);
#pragma unroll
  for (int d4 = 0; d4 < 16; ++d4) {
    float4 v = xp[d4];
    xr[d4 * 4 + 0] = v.x; xr[d4 * 4 + 1] = v.y; xr[d4 * 4 + 2] = v.z; xr[d4 * 4 + 3] = v.w;
  }
  __syncthreads();
  for (int i = 0; i < 64; ++i) {
    int hh = (q << 6) + i;
    float acc = bias[hh];
#pragma unroll
    for (int d = 0; d < DIN; ++d) acc = fmaf(xr[d], wlds[d * H_SZ + hh], acc);
    hbuf[(b * H_SZ + hh) * L_SZ + l] = acc;
  }
}

// ---------------- convert w_out to bf16 ----------------
__global__ void k_cvtw(const float* __restrict__ w, unsigned short* __restrict__ wbf, int n) {
  int i = blockIdx.x * 256 + threadIdx.x;
  if (i < n) wbf[i] = f2b(w[i]);
}

// ---------------- per-layer phase 1: local chunk scans (state only) ----------------
__global__ void k_scan_local(const float* __restrict__ hbuf, float2* __restrict__ sF,
                             const float* __restrict__ log_dt,
                             const float* __restrict__ log_A_real,
                             const float* __restrict__ A_imag) {
  int gt = blockIdx.x * 256 + threadIdx.x;  // ((b*NT+c)*H + h)*4 + ng
  int ng = gt & 3;
  int h = (gt >> 2) & 255;
  int c = (gt >> 10) & 15;
  int b = gt >> 14;
  float dt = expf(log_dt[h]);
  float lr[8], li[8], sre[8], sim[8];
#pragma unroll
  for (int k = 0; k < 8; ++k) {
    int n = ng * 8 + k;
    float Ar = -expf(log_A_real[h * NH + n]);
    float Ai = A_imag[h * NH + n];
    float e = expf(dt * Ar), sn, cs;
    sincosf(dt * Ai, &sn, &cs);
    lr[k] = e * cs; li[k] = e * sn;
    sre[k] = 0.f; sim[k] = 0.f;
  }
  const float* xp = hbuf + (b * H_SZ + h) * L_SZ + c * TC;
  float4 xv = *(const float4*)xp;
  for (int j4 = 0; j4 < TC; j4 += 4) {
    float4 xn = xv;
    if (j4 + 4 < TC) xn = *(const float4*)(xp + j4 + 4);
    float xe[4] = {xv.x, xv.y, xv.z, xv.w};
#pragma unroll
    for (int e = 0; e < 4; ++e) {
      float xj = xe[e];
#pragma unroll
      for (int k = 0; k < 8; ++k) {
        float nr = fmaf(lr[k], sre[k], xj);
        nr = fmaf(-li[k], sim[k], nr);
        float ni = lr[k] * sim[k];
        ni = fmaf(li[k], sre[k], ni);
        sre[k] = nr; sim[k] = ni;
      }
    }
    xv = xn;
  }
  float2* out = sF + ((size_t)(b * H_SZ + h) * NTC + c) * NH + ng * 8;
#pragma unroll
  for (int k = 0; k < 8; ++k) out[k] = make_float2(sre[k], sim[k]);
}

// ---------------- per-layer fused: carry + recurrence + gelu + matmul/GLU + residual + LN ----------------
__launch_bounds__(1024)
__global__ void k_layer(float* __restrict__ hbuf, const float2* __restrict__ sF,
                        const float* __restrict__ log_dt,
                        const float* __restrict__ C_re, const float* __restrict__ C_im,
                        const float* __restrict__ log_A_real, const float* __restrict__ A_imag,
                        const float* __restrict__ D_skip,
                        const unsigned short* __restrict__ wbf,
                        const float* __restrict__ b_out,
                        const float* __restrict__ ln_g, const float* __restrict__ ln_b) {
  __shared__ __align__(16) unsigned short yt[TC][H_SZ + 8];  // 67.6 KB; y -> z (bf16)
  __shared__ float part[TC][8][2];
  __shared__ float stats[TC][2];
  int tid = threadIdx.x;
  int b = blockIdx.x >> 4;
  int c = blockIdx.x & 15;
  int l0 = c * TC;

  // ---- phase 1: recurrence with carry-in; write y+skip (pre-gelu) to LDS ----
  {
    int h = tid >> 2, ng = tid & 3;
    float dt = expf(log_dt[h]);
    float lr[8], li[8], c2r[8], c2i[8], sre[8], sim[8], lTr[8], lTi[8];
#pragma unroll
    for (int k = 0; k < 8; ++k) {
      int n = ng * 8 + k;
      float Ar = -expf(log_A_real[h * NH + n]);
      float Ai = A_imag[h * NH + n];
      float dr = dt * Ar, di = dt * Ai;
      float e = expf(dr), sn, cs;
      sincosf(di, &sn, &cs);
      lr[k] = e * cs; li[k] = e * sn;
      float eT = expf((float)TC * dr), snT, csT;
      sincosf((float)TC * di, &snT, &csT);
      lTr[k] = eT * csT; lTi[k] = eT * snT;
      float wr = lr[k] - 1.f, wi = li[k];
      float Cr = C_re[h * NH + n], Ci = C_im[h * NH + n];
      float pr = Cr * wr - Ci * wi;
      float pi = Cr * wi + Ci * wr;
      float inv = 2.f / fmaf(Ar, Ar, Ai * Ai);
      c2r[k] = (pr * Ar + pi * Ai) * inv;
      c2i[k] = (pi * Ar - pr * Ai) * inv;
      sre[k] = 0.f; sim[k] = 0.f;
    }
    // carry-in: scan local finals of chunks < c (redundant per block, cheap)
    const float2* sfp = sF + (size_t)(b * H_SZ + h) * NTC * NH + ng * 8;
    for (int cc = 0; cc < c; ++cc) {
#pragma unroll
      for (int k = 0; k < 8; ++k) {
        float2 f = sfp[cc * NH + k];
        float nr = lTr[k] * sre[k] - lTi[k] * sim[k] + f.x;
        float ni = lTr[k] * sim[k] + lTi[k] * sre[k] + f.y;
        sre[k] = nr; sim[k] = ni;
      }
    }
    float Dh = D_skip[h];
    const float* xp = hbuf + (b * H_SZ + h) * L_SZ + l0;
    float4 xv = *(const float4*)xp;
    for (int j4 = 0; j4 < TC; j4 += 4) {
      float4 xn = xv;
      if (j4 + 4 < TC) xn = *(const float4*)(xp + j4 + 4);
      float xe[4] = {xv.x, xv.y, xv.z, xv.w};
#pragma unroll
      for (int e = 0; e < 4; ++e) {
        float xj = xe[e];
        float yp = 0.f;
#pragma unroll
        for (int k = 0; k < 8; ++k) {
          float nr = fmaf(lr[k], sre[k], xj);
          nr = fmaf(-li[k], sim[k], nr);
          float ni = lr[k] * sim[k];
          ni = fmaf(li[k], sre[k], ni);
          sre[k] = nr; sim[k] = ni;
          yp = fmaf(c2r[k], nr, yp);
          yp = fmaf(-c2i[k], ni, yp);
        }
        yp += __shfl_xor(yp, 1);
        yp += __shfl_xor(yp, 2);
        if (ng == 0) yt[j4 + e][h] = f2b(fmaf(Dh, xj, yp));
      }
      xv = xn;
    }
  }
  __syncthreads();
  // ---- phase 2: exact GELU in place ----
  for (int it = 0; it < 32; ++it) {
    int id = it * 1024 + tid;
    int j = id >> 8, hh = id & 255;
    float v = b2f(yt[j][hh]);
    yt[j][hh] = f2b(0.5f * v * (1.f + erff(v * 0.70710678118654752f)));
  }
  __syncthreads();
  // ---- phase 3: 1x1 conv (512x256 @ 256x128) via MFMA + GLU; z -> LDS ----
  {
    int w = tid >> 6, lane = tid & 63;
    int lrow = lane & 15, lk8 = (lane >> 4) << 3;
    f32x4 accA[8], accG[8];
    f32x4 zed = {0.f, 0.f, 0.f, 0.f};
#pragma unroll
    for (int jt = 0; jt < 8; ++jt) { accA[jt] = zed; accG[jt] = zed; }
    const unsigned short* wA = wbf + ((w << 4) + lrow) * H_SZ;
    const unsigned short* wG = wA + 256 * H_SZ;
#pragma unroll
    for (int k0 = 0; k0 < H_SZ; k0 += 32) {
      bf16x8 a0 = *(const bf16x8*)(wA + k0 + lk8);
      bf16x8 a1 = *(const bf16x8*)(wG + k0 + lk8);
#pragma unroll
      for (int jt = 0; jt < 8; ++jt) {
        bf16x8 bb = *(const bf16x8*)(&yt[(jt << 4) + lrow][k0 + lk8]);
        accA[jt] = __builtin_amdgcn_mfma_f32_16x16x32_bf16(a0, bb, accA[jt], 0, 0, 0);
        accG[jt] = __builtin_amdgcn_mfma_f32_16x16x32_bf16(a1, bb, accG[jt], 0, 0, 0);
      }
    }
    __syncthreads();  // all y reads done before overwrite with z
    int rbase = (lane >> 4) << 2;
    float bA[4], bG[4];
#pragma unroll
    for (int r = 0; r < 4; ++r) {
      bA[r] = b_out[(w << 4) + rbase + r];
      bG[r] = b_out[256 + (w << 4) + rbase + r];
    }
#pragma unroll
    for (int jt = 0; jt < 8; ++jt) {
#pragma unroll
      for (int r = 0; r < 4; ++r) {
        float a = accA[jt][r] + bA[r];
        float g = accG[jt][r] + bG[r];
        float z = a / (1.f + expf(-g));
        yt[(jt << 4) + lrow][(w << 4) + rbase + r] = f2b(z);
      }
    }
  }
  __syncthreads();
  // ---- phase 4: LN stats over H for each column j (v = z + h_res) ----
  {
    int j = tid >> 3, hg = tid & 7;
    const float* xc = hbuf + (b * H_SZ + (hg << 5)) * L_SZ + l0 + j;
    float s = 0.f, sq = 0.f;
#pragma unroll
    for (int k = 0; k < 32; ++k) {
      float v = b2f(yt[j][(hg << 5) + k]) + xc[k * L_SZ];
      s += v; sq = fmaf(v, v, sq);
    }
    part[j][hg][0] = s; part[j][hg][1] = sq;
  }
  __syncthreads();
  if (tid < TC) {
    float s = 0.f, sq = 0.f;
#pragma unroll
    for (int g8 = 0; g8 < 8; ++g8) { s += part[tid][g8][0]; sq += part[tid][g8][1]; }
    float mu = s * (1.f / 256.f);
    float var = sq * (1.f / 256.f) - mu * mu;
    stats[tid][0] = mu;
    stats[tid][1] = rsqrtf(var + 1e-5f);
  }
  __syncthreads();
  // ---- phase 5: normalized residual write (in place; block-local region) ----
  for (int it = 0; it < 32; ++it) {
    int id = it * 1024 + tid;
    int j = id & 127, hh = id >> 7;
    int gi = (b * H_SZ + hh) * L_SZ + l0 + j;
    float v = b2f(yt[j][hh]) + hbuf[gi];
    hbuf[gi] = (v - stats[j][0]) * stats[j][1] * ln_g[hh] + ln_b[hh];
  }
}

// ---------------- mean pool over L ----------------
__global__ void k_pool(const float* __restrict__ hbuf, float* __restrict__ pooled) {
  int bh = blockIdx.x;
  int lane = threadIdx.x;
  const float* p = hbuf + (size_t)bh * L_SZ;
  float s = 0.f;
  for (int k = 0; k < L_SZ / 64; ++k) s += p[lane + (k << 6)];
#pragma unroll
  for (int off = 32; off > 0; off >>= 1) s += __shfl_xor(s, off);
  if (lane == 0) pooled[bh] = s * (1.f / 2048.f);
}

// ---------------- decoder MLP (single block) ----------------
__global__ void k_decoder(const float* __restrict__ pooled,
                          const float* __restrict__ w1, const float* __restrict__ b1,
                          const float* __restrict__ w2, const float* __restrict__ b2,
                          const float* __restrict__ w3, const float* __restrict__ b3,
                          float* __restrict__ out) {
  __shared__ float P[16 * 256];
  __shared__ float O1[16 * 128];
  __shared__ float O2[16 * 64];
  int tid = threadIdx.x;
  for (int i = tid; i < 16 * 256; i += 256) P[i] = pooled[i];
  __syncthreads();
  for (int id = tid; id < 16 * 128; id += 256) {
    int r = id >> 7, cc = id & 127;
    float acc = b1[cc];
    for (int d = 0; d < 256; ++d) acc = fmaf(P[(r << 8) + d], w1[(d << 7) + cc], acc);
    O1[id] = fmaxf(acc, 0.f);
  }
  __syncthreads();
  for (int id = tid; id < 16 * 64; id += 256) {
    int r = id >> 6, cc = id & 63;
    float acc = b2[cc];
    for (int d = 0; d < 128; ++d) acc = fmaf(O1[(r << 7) + d], w2[(d << 6) + cc], acc);
    O2[id] = fmaxf(acc, 0.f);
  }
  __syncthreads();
  for (int id = tid; id < 16 * 32; id += 256) {
    int r = id >> 5, cc = id & 31;
    float acc = b3[cc];
    for (int d = 0; d < 64; ++d) acc = fmaf(O2[(r << 6) + d], w3[(d << 5) + cc], acc);
    out[id] = acc;
  }
}

extern "C" void kernel_launch(void* const* d_in, const int* in_sizes, int n_in,
                              void* d_out, int out_size, void* d_ws, size_t ws_size,
                              hipStream_t stream) {
  const float* x          = (const float*)d_in[0];
  const float* enc_w      = (const float*)d_in[1];
  const float* enc_b      = (const float*)d_in[2];
  const float* log_dt     = (const float*)d_in[3];
  const float* C_re       = (const float*)d_in[4];
  const float* C_im       = (const float*)d_in[5];
  const float* log_A_real = (const float*)d_in[6];
  const float* A_imag     = (const float*)d_in[7];
  const float* D_skip     = (const float*)d_in[8];
  const float* w_out      = (const float*)d_in[9];
  const float* b_out      = (const float*)d_in[10];
  const float* ln_g       = (const float*)d_in[11];
  const float* ln_b       = (const float*)d_in[12];
  const float* dw1        = (const float*)d_in[13];
  const float* db1        = (const float*)d_in[14];
  const float* dw2        = (const float*)d_in[15];
  const float* db2        = (const float*)d_in[16];
  const float* dw3        = (const float*)d_in[17];
  const float* db3        = (const float*)d_in[18];

  char* ws = (char*)d_ws;
  float* hbuf = (float*)ws;                                  // 33,554,432 B
  float2* sF = (float2*)(ws + 33554432);                     // 16,777,216 B
  unsigned short* wbf = (unsigned short*)(ws + 50331648);    //  1,048,576 B
  float* pooled = (float*)(ws + 51380224);                   //     16,384 B

  k_encoder<<<512, 256, 0, stream>>>(x, enc_w, enc_b, hbuf);
  k_cvtw<<<2048, 256, 0, stream>>>(w_out, wbf, NL * 512 * H_SZ);
  for (int i = 0; i < NL; ++i) {
    k_scan_local<<<1024, 256, 0, stream>>>(hbuf, sF, log_dt + i * H_SZ,
                                           log_A_real + i * H_SZ * NH, A_imag + i * H_SZ * NH);
    k_layer<<<256, 1024, 0, stream>>>(hbuf, sF, log_dt + i * H_SZ,
                                      C_re + i * H_SZ * NH, C_im + i * H_SZ * NH,
                                      log_A_real + i * H_SZ * NH, A_imag + i * H_SZ * NH,
                                      D_skip + i * H_SZ, wbf + i * 512 * H_SZ,
                                      b_out + i * 512, ln_g + i * H_SZ, ln_b + i * H_SZ);
  }
  k_pool<<<4096, 64, 0, stream>>>(hbuf, pooled);
  k_decoder<<<1, 256, 0, stream>>>(pooled, dw1, db1, dw2, db2, dw3, db3, (float*)d_out);
}

// Round 2
// 665.044 us; speedup vs baseline: 1.0971x; 1.0971x over previous
//
#include <hip/hip_runtime.h>

#define B_SZ 16
#define L_SZ 2048
#define DIN 64
#define H_SZ 256
#define NH 32
#define NL 4
#define TC 128
#define NTC 16

typedef __attribute__((ext_vector_type(8))) __bf16 bf16x8;
typedef __attribute__((ext_vector_type(4))) float f32x4;

__device__ __forceinline__ unsigned short f2b(float f) {
  unsigned int u = __builtin_bit_cast(unsigned int, f);
  unsigned int r = u + 0x7fffu + ((u >> 16) & 1u);  // RNE (no NaN inputs here)
  return (unsigned short)(r >> 16);
}
__device__ __forceinline__ float b2f(unsigned short u) {
  unsigned int v = ((unsigned int)u) << 16;
  return __builtin_bit_cast(float, v);
}

// ---------------- encoder: h[b][hh][l] = x[b][l][:] @ enc_w[:,hh] + enc_b ----------------
__global__ void k_encoder(const float* __restrict__ x, const float* __restrict__ w,
                          const float* __restrict__ bias, float* __restrict__ hbuf) {
  __shared__ float wlds[DIN * H_SZ];  // 64 KB
  int tid = threadIdx.x;
  for (int i = tid; i < DIN * H_SZ; i += 256) wlds[i] = w[i];
  int blk = blockIdx.x;            // 512 blocks: b(16) x q(4) x ltile(8)
  int b = blk >> 5;
  int q = (blk >> 3) & 3;
  int l = ((blk & 7) << 8) + tid;
  float xr[DIN];
  const float4* xp = (const float4*)(x + (size_t)(b * L_SZ + l) * DIN);
#pragma unroll
  for (int d4 = 0; d4 < 16; ++d4) {
    float4 v = xp[d4];
    xr[d4 * 4 + 0] = v.x; xr[d4 * 4 + 1] = v.y; xr[d4 * 4 + 2] = v.z; xr[d4 * 4 + 3] = v.w;
  }
  __syncthreads();
  for (int i = 0; i < 64; ++i) {
    int hh = (q << 6) + i;
    float acc = bias[hh];
#pragma unroll
    for (int d = 0; d < DIN; ++d) acc = fmaf(xr[d], wlds[d * H_SZ + hh], acc);
    hbuf[(b * H_SZ + hh) * L_SZ + l] = acc;
  }
}

// ---------------- convert w_out to bf16 ----------------
__global__ void k_cvtw(const float* __restrict__ w, unsigned short* __restrict__ wbf, int n) {
  int i = blockIdx.x * 256 + threadIdx.x;
  if (i < n) wbf[i] = f2b(w[i]);
}

// ---------------- precompute per-state params: lr, li, c2r, c2i, lTr, lTi ----------------
__global__ void k_params(const float* __restrict__ log_dt, const float* __restrict__ log_A_real,
                         const float* __restrict__ A_imag, const float* __restrict__ C_re,
                         const float* __restrict__ C_im, float* __restrict__ par) {
  int id = blockIdx.x * 256 + threadIdx.x;  // i*8192 + h*32 + n
  if (id >= NL * H_SZ * NH) return;
  int i = id >> 13;
  int hn = id & 8191;
  int h = hn >> 5;
  float dt = expf(log_dt[i * H_SZ + h]);
  float Ar = -expf(log_A_real[(size_t)i * H_SZ * NH + hn]);
  float Ai = A_imag[(size_t)i * H_SZ * NH + hn];
  float dr = dt * Ar, di = dt * Ai;
  float e = expf(dr), sn, cs;
  sincosf(di, &sn, &cs);
  float lr = e * cs, li = e * sn;
  float eT = expf((float)TC * dr), snT, csT;
  sincosf((float)TC * di, &snT, &csT);
  float Cr = C_re[(size_t)i * H_SZ * NH + hn], Ci = C_im[(size_t)i * H_SZ * NH + hn];
  float wr = lr - 1.f, wi = li;
  float pr = Cr * wr - Ci * wi;
  float pi = Cr * wi + Ci * wr;
  float inv = 2.f / fmaf(Ar, Ar, Ai * Ai);
  float4* p = (float4*)(par + (size_t)id * 8);
  p[0] = make_float4(lr, li, (pr * Ar + pi * Ai) * inv, (pi * Ar - pr * Ai) * inv);
  p[1] = make_float4(eT * csT, eT * snT, 0.f, 0.f);
}

// ---------------- per-layer phase 1: local chunk scans (state only) ----------------
__global__ void k_scan_local(const float* __restrict__ hbuf, float2* __restrict__ sF,
                             const float* __restrict__ par) {
  int gt = blockIdx.x * 256 + threadIdx.x;  // ((b*NT+c)*H + h)*4 + ng
  int ng = gt & 3;
  int h = (gt >> 2) & 255;
  int c = (gt >> 10) & 15;
  int b = gt >> 14;
  float lr[8], li[8], sre[8], sim[8];
  const float4* pp = (const float4*)(par + (size_t)(h * NH + ng * 8) * 8);
#pragma unroll
  for (int k = 0; k < 8; ++k) {
    float4 p0 = pp[k * 2];
    lr[k] = p0.x; li[k] = p0.y;
    sre[k] = 0.f; sim[k] = 0.f;
  }
  const float* xp = hbuf + (b * H_SZ + h) * L_SZ + c * TC;
  float4 xv = *(const float4*)xp;
  for (int j4 = 0; j4 < TC; j4 += 4) {
    float4 xn = xv;
    if (j4 + 4 < TC) xn = *(const float4*)(xp + j4 + 4);
    float xe[4] = {xv.x, xv.y, xv.z, xv.w};
#pragma unroll
    for (int e = 0; e < 4; ++e) {
      float xj = xe[e];
#pragma unroll
      for (int k = 0; k < 8; ++k) {
        float nr = fmaf(lr[k], sre[k], xj);
        nr = fmaf(-li[k], sim[k], nr);
        float ni = lr[k] * sim[k];
        ni = fmaf(li[k], sre[k], ni);
        sre[k] = nr; sim[k] = ni;
      }
    }
    xv = xn;
  }
  float2* out = sF + ((size_t)(b * H_SZ + h) * NTC + c) * NH + ng * 8;
#pragma unroll
  for (int k = 0; k < 8; ++k) out[k] = make_float2(sre[k], sim[k]);
}

// ---------------- per-layer fused: carry + recurrence + gelu + matmul/GLU + residual + LN ----------------
__launch_bounds__(1024)
__global__ void k_layer(float* __restrict__ hbuf, const float2* __restrict__ sF,
                        const float* __restrict__ par,
                        const float* __restrict__ D_skip,
                        const unsigned short* __restrict__ wbf,
                        const float* __restrict__ b_out,
                        const float* __restrict__ ln_g, const float* __restrict__ ln_b) {
  __shared__ __align__(16) unsigned short yt[TC][H_SZ + 8];  // 67.6 KB; y -> z (bf16)
  __shared__ float part[TC][8][2];
  __shared__ float stats[TC][2];
  int tid = threadIdx.x;
  int b = blockIdx.x >> 4;
  int c = blockIdx.x & 15;
  int l0 = c * TC;

  // ---- phase 1: recurrence with carry-in; write y+skip (pre-gelu) to LDS ----
  {
    int h = tid >> 2, ng = tid & 3;
    float lr[8], li[8], c2r[8], c2i[8], sre[8], sim[8], lTr[8], lTi[8];
    const float4* pp = (const float4*)(par + (size_t)(h * NH + ng * 8) * 8);
#pragma unroll
    for (int k = 0; k < 8; ++k) {
      float4 p0 = pp[k * 2];
      float4 p1 = pp[k * 2 + 1];
      lr[k] = p0.x; li[k] = p0.y; c2r[k] = p0.z; c2i[k] = p0.w;
      lTr[k] = p1.x; lTi[k] = p1.y;
      sre[k] = 0.f; sim[k] = 0.f;
    }
    // carry-in: scan local finals of chunks < c (redundant per block, cheap)
    const float2* sfp = sF + (size_t)(b * H_SZ + h) * NTC * NH + ng * 8;
    for (int cc = 0; cc < c; ++cc) {
#pragma unroll
      for (int k = 0; k < 8; ++k) {
        float2 f = sfp[cc * NH + k];
        float nr = lTr[k] * sre[k] - lTi[k] * sim[k] + f.x;
        float ni = lTr[k] * sim[k] + lTi[k] * sre[k] + f.y;
        sre[k] = nr; sim[k] = ni;
      }
    }
    float Dh = D_skip[h];
    const float* xp = hbuf + (b * H_SZ + h) * L_SZ + l0;
    float4 xv = *(const float4*)xp;
    for (int j4 = 0; j4 < TC; j4 += 4) {
      float4 xn = xv;
      if (j4 + 4 < TC) xn = *(const float4*)(xp + j4 + 4);
      float xe[4] = {xv.x, xv.y, xv.z, xv.w};
#pragma unroll
      for (int e = 0; e < 4; ++e) {
        float xj = xe[e];
        float yp0 = 0.f, yp1 = 0.f;
#pragma unroll
        for (int k = 0; k < 8; ++k) {
          float nr = fmaf(lr[k], sre[k], xj);
          nr = fmaf(-li[k], sim[k], nr);
          float ni = lr[k] * sim[k];
          ni = fmaf(li[k], sre[k], ni);
          sre[k] = nr; sim[k] = ni;
          if (k & 1) {
            yp1 = fmaf(c2r[k], nr, yp1);
            yp1 = fmaf(-c2i[k], ni, yp1);
          } else {
            yp0 = fmaf(c2r[k], nr, yp0);
            yp0 = fmaf(-c2i[k], ni, yp0);
          }
        }
        float yp = yp0 + yp1;
        yp += __shfl_xor(yp, 1);
        yp += __shfl_xor(yp, 2);
        if (ng == 0) yt[j4 + e][h] = f2b(fmaf(Dh, xj, yp));
      }
      xv = xn;
    }
  }
  __syncthreads();
  // ---- phase 2: exact GELU in place ----
  for (int it = 0; it < 32; ++it) {
    int id = it * 1024 + tid;
    int j = id >> 8, hh = id & 255;
    float v = b2f(yt[j][hh]);
    yt[j][hh] = f2b(0.5f * v * (1.f + erff(v * 0.70710678118654752f)));
  }
  __syncthreads();
  // ---- phase 3: 1x1 conv (512x256 @ 256x128) via MFMA + GLU; z -> LDS ----
  {
    int w = tid >> 6, lane = tid & 63;
    int lrow = lane & 15, lk8 = (lane >> 4) << 3;
    f32x4 accA[8], accG[8];
    f32x4 zed = {0.f, 0.f, 0.f, 0.f};
#pragma unroll
    for (int jt = 0; jt < 8; ++jt) { accA[jt] = zed; accG[jt] = zed; }
    const unsigned short* wA = wbf + ((w << 4) + lrow) * H_SZ;
    const unsigned short* wG = wA + 256 * H_SZ;
#pragma unroll
    for (int k0 = 0; k0 < H_SZ; k0 += 32) {
      bf16x8 a0 = *(const bf16x8*)(wA + k0 + lk8);
      bf16x8 a1 = *(const bf16x8*)(wG + k0 + lk8);
#pragma unroll
      for (int jt = 0; jt < 8; ++jt) {
        bf16x8 bb = *(const bf16x8*)(&yt[(jt << 4) + lrow][k0 + lk8]);
        accA[jt] = __builtin_amdgcn_mfma_f32_16x16x32_bf16(a0, bb, accA[jt], 0, 0, 0);
        accG[jt] = __builtin_amdgcn_mfma_f32_16x16x32_bf16(a1, bb, accG[jt], 0, 0, 0);
      }
    }
    __syncthreads();  // all y reads done before overwrite with z
    int rbase = (lane >> 4) << 2;
    float bA[4], bG[4];
#pragma unroll
    for (int r = 0; r < 4; ++r) {
      bA[r] = b_out[(w << 4) + rbase + r];
      bG[r] = b_out[256 + (w << 4) + rbase + r];
    }
#pragma unroll
    for (int jt = 0; jt < 8; ++jt) {
#pragma unroll
      for (int r = 0; r < 4; ++r) {
        float a = accA[jt][r] + bA[r];
        float g = accG[jt][r] + bG[r];
        float z = a / (1.f + expf(-g));
        yt[(jt << 4) + lrow][(w << 4) + rbase + r] = f2b(z);
      }
    }
  }
  __syncthreads();
  // ---- phase 4: LN stats over H (coalesced); keep v in registers ----
  int j = tid & 127, hg = tid >> 7;  // 8 groups of 32 h
  float vreg[32];
  {
    const float* xc = hbuf + (b * H_SZ + (hg << 5)) * L_SZ + l0 + j;
    float s = 0.f, sq = 0.f;
#pragma unroll
    for (int k = 0; k < 32; ++k) {
      float v = b2f(yt[j][(hg << 5) + k]) + xc[(size_t)k * L_SZ];
      vreg[k] = v;
      s += v; sq = fmaf(v, v, sq);
    }
    part[j][hg][0] = s; part[j][hg][1] = sq;
  }
  __syncthreads();
  if (tid < TC) {
    float s = 0.f, sq = 0.f;
#pragma unroll
    for (int g8 = 0; g8 < 8; ++g8) { s += part[tid][g8][0]; sq += part[tid][g8][1]; }
    float mu = s * (1.f / 256.f);
    float var = sq * (1.f / 256.f) - mu * mu;
    stats[tid][0] = mu;
    stats[tid][1] = rsqrtf(var + 1e-5f);
  }
  __syncthreads();
  // ---- phase 5: normalized residual write from registers (coalesced) ----
  {
    float mu = stats[j][0], rs = stats[j][1];
    float* xo = hbuf + (b * H_SZ + (hg << 5)) * L_SZ + l0 + j;
#pragma unroll
    for (int k = 0; k < 32; ++k) {
      int hh = (hg << 5) + k;
      xo[(size_t)k * L_SZ] = (vreg[k] - mu) * rs * ln_g[hh] + ln_b[hh];
    }
  }
}

// ---------------- mean pool over L ----------------
__global__ void k_pool(const float* __restrict__ hbuf, float* __restrict__ pooled) {
  int bh = blockIdx.x;
  int lane = threadIdx.x;
  const float* p = hbuf + (size_t)bh * L_SZ;
  float s = 0.f;
  for (int k = 0; k < L_SZ / 64; ++k) s += p[lane + (k << 6)];
#pragma unroll
  for (int off = 32; off > 0; off >>= 1) s += __shfl_xor(s, off);
  if (lane == 0) pooled[bh] = s * (1.f / 2048.f);
}

// ---------------- decoder MLP (single block) ----------------
__global__ void k_decoder(const float* __restrict__ pooled,
                          const float* __restrict__ w1, const float* __restrict__ b1,
                          const float* __restrict__ w2, const float* __restrict__ b2,
                          const float* __restrict__ w3, const float* __restrict__ b3,
                          float* __restrict__ out) {
  __shared__ float P[16 * 256];
  __shared__ float O1[16 * 128];
  __shared__ float O2[16 * 64];
  int tid = threadIdx.x;
  for (int i = tid; i < 16 * 256; i += 256) P[i] = pooled[i];
  __syncthreads();
  for (int id = tid; id < 16 * 128; id += 256) {
    int r = id >> 7, cc = id & 127;
    float acc = b1[cc];
    for (int d = 0; d < 256; ++d) acc = fmaf(P[(r << 8) + d], w1[(d << 7) + cc], acc);
    O1[id] = fmaxf(acc, 0.f);
  }
  __syncthreads();
  for (int id = tid; id < 16 * 64; id += 256) {
    int r = id >> 6, cc = id & 63;
    float acc = b2[cc];
    for (int d = 0; d < 128; ++d) acc = fmaf(O1[(r << 7) + d], w2[(d << 6) + cc], acc);
    O2[id] = fmaxf(acc, 0.f);
  }
  __syncthreads();
  for (int id = tid; id < 16 * 32; id += 256) {
    int r = id >> 5, cc = id & 31;
    float acc = b3[cc];
    for (int d = 0; d < 64; ++d) acc = fmaf(O2[(r << 6) + d], w3[(d << 5) + cc], acc);
    out[id] = acc;
  }
}

extern "C" void kernel_launch(void* const* d_in, const int* in_sizes, int n_in,
                              void* d_out, int out_size, void* d_ws, size_t ws_size,
                              hipStream_t stream) {
  const float* x          = (const float*)d_in[0];
  const float* enc_w      = (const float*)d_in[1];
  const float* enc_b      = (const float*)d_in[2];
  const float* log_dt     = (const float*)d_in[3];
  const float* C_re       = (const float*)d_in[4];
  const float* C_im       = (const float*)d_in[5];
  const float* log_A_real = (const float*)d_in[6];
  const float* A_imag     = (const float*)d_in[7];
  const float* D_skip     = (const float*)d_in[8];
  const float* w_out      = (const float*)d_in[9];
  const float* b_out      = (const float*)d_in[10];
  const float* ln_g       = (const float*)d_in[11];
  const float* ln_b       = (const float*)d_in[12];
  const float* dw1        = (const float*)d_in[13];
  const float* db1        = (const float*)d_in[14];
  const float* dw2        = (const float*)d_in[15];
  const float* db2        = (const float*)d_in[16];
  const float* dw3        = (const float*)d_in[17];
  const float* db3        = (const float*)d_in[18];

  char* ws = (char*)d_ws;
  float* hbuf = (float*)ws;                                  // 33,554,432 B
  float2* sF = (float2*)(ws + 33554432);                     // 16,777,216 B
  unsigned short* wbf = (unsigned short*)(ws + 50331648);    //  1,048,576 B
  float* pooled = (float*)(ws + 51380224);                   //     16,384 B
  float* par = (float*)(ws + 51396608);                      //  1,048,576 B

  k_encoder<<<512, 256, 0, stream>>>(x, enc_w, enc_b, hbuf);
  k_cvtw<<<2048, 256, 0, stream>>>(w_out, wbf, NL * 512 * H_SZ);
  k_params<<<128, 256, 0, stream>>>(log_dt, log_A_real, A_imag, C_re, C_im, par);
  for (int i = 0; i < NL; ++i) {
    const float* pari = par + (size_t)i * H_SZ * NH * 8;
    k_scan_local<<<1024, 256, 0, stream>>>(hbuf, sF, pari);
    k_layer<<<256, 1024, 0, stream>>>(hbuf, sF, pari,
                                      D_skip + i * H_SZ, wbf + i * 512 * H_SZ,
                                      b_out + i * 512, ln_g + i * H_SZ, ln_b + i * H_SZ);
  }
  k_pool<<<4096, 64, 0, stream>>>(hbuf, pooled);
  k_decoder<<<1, 256, 0, stream>>>(pooled, dw1, db1, dw2, db2, dw3, db3, (float*)d_out);
}